// Round 22
// baseline (424.338 us; speedup 1.0000x reference)
//
#include <hip/hip_runtime.h>
#include <math.h>

#define N_NODES 50000
#define N_EDGES 500000
#define D 128
#define H 256
#define NE 64
#define TOPK 2
#define NPAIR (N_NODES * TOPK)
#define CAP 3126               // 2 * ceil(100000/64)
#define TILE_R 32
#define BQ 16                  // blocks per expert in k_moe (1024 blocks = 4/CU)
#define BN_NBLK 128
#define BN_ROWS ((N_NODES + BN_NBLK - 1) / BN_NBLK) // 391

typedef __attribute__((ext_vector_type(8))) short s16x8;
typedef __attribute__((ext_vector_type(4))) float f32x4;

__device__ __forceinline__ unsigned short f2bf(float f) {
    unsigned u = __float_as_uint(f);
    unsigned r = (u + 0x7fffu + ((u >> 16) & 1u)) >> 16;
    return (unsigned short)r;
}
__device__ __forceinline__ float bf2f(unsigned short u) {
    return __uint_as_float(((unsigned)u) << 16);
}

// gelu(x) = 0.5x(1+erf(x/sqrt2)); erf via A&S 7.1.26 (|err|<=1.5e-7 << bf16 quant)
__device__ __forceinline__ float gelu_f(float x) {
    float u = 0.70710678118654752f * x;
    float au = fabsf(u);
    float t = 1.0f / fmaf(0.3275911f, au, 1.0f);
    float poly = t * fmaf(t, fmaf(t, fmaf(t, fmaf(t, 1.061405429f, -1.453152027f),
                      1.421413741f), -0.284496736f), 0.254829592f);
    float e = __expf(-u * u);
    float erfa = 1.0f - poly * e;
    float erfu = copysignf(erfa, u);
    return 0.5f * x * (1.0f + erfu);
}

// Compensated f32: TwoProd (mul + fma residual) + branch-free TwoSum.
#define DOT2(s, c, xx, ww) {                      \
    float p_ = (xx) * (ww);                       \
    float e1_ = fmaf((xx), (ww), -p_);            \
    float t_ = (s) + p_;                          \
    float z_ = t_ - (s);                          \
    float e2_ = ((s) - (t_ - z_)) + (p_ - z_);    \
    (s) = t_;                                     \
    (c) += e1_ + e2_; }

#define TSUM(s, c, pp) {                          \
    float p_ = (pp);                              \
    float t_ = (s) + p_;                          \
    float z_ = t_ - (s);                          \
    float e2_ = ((s) - (t_ - z_)) + (p_ - z_);    \
    (s) = t_;                                     \
    (c) += e2_; }

// Kahan add: 4 ops; order-variation ~1e-7 rel (covered by gate TAU band)
#define KAH(s, c, pp) {                           \
    float y_ = (pp) - (c);                        \
    float t_ = (s) + y_;                          \
    (c) = (t_ - (s)) - y_;                        \
    (s) = t_; }

// ---------------- degree count ----------------
__global__ void k_deg(const int* __restrict__ dst, int* __restrict__ deg) {
    int i = blockIdx.x * blockDim.x + threadIdx.x;
    if (i < N_EDGES) atomicAdd(&deg[dst[i]], 1);
}

__global__ void k_invsqrt(const int* __restrict__ deg, float* __restrict__ invs) {
    int i = blockIdx.x * blockDim.x + threadIdx.x;
    if (i < N_NODES) {
        double d = (double)deg[i];
        if (d < 1.0) d = 1.0;
        invs[i] = (float)(1.0 / sqrt(d));
    }
}

// ---------------- exclusive scan of deg -> rowptr ----------------
__global__ __launch_bounds__(1024) void k_scan(const int* __restrict__ deg,
                                               int* __restrict__ rowptr) {
    __shared__ int sh[1024];
    int t = threadIdx.x;
    const int chunk = (N_NODES + 1023) / 1024;   // 49
    int lo = t * chunk;
    int hi = min(lo + chunk, N_NODES);
    int s = 0;
    for (int i = lo; i < hi; i++) s += deg[i];
    sh[t] = s;
    __syncthreads();
    for (int off = 1; off < 1024; off <<= 1) {
        int v = (t >= off) ? sh[t - off] : 0;
        __syncthreads();
        sh[t] += v;
        __syncthreads();
    }
    int run = (t == 0) ? 0 : sh[t - 1];
    for (int i = lo; i < hi; i++) { rowptr[i] = run; run += deg[i]; }
    if (t == 1023) rowptr[N_NODES] = run;
}

// ---------------- scatter edges into CSR ----------------
__global__ void k_scatter(const int* __restrict__ src, const int* __restrict__ dst,
                          const int* __restrict__ rowptr, int* __restrict__ cursor,
                          int* __restrict__ csr) {
    int e = blockIdx.x * blockDim.x + threadIdx.x;
    if (e >= N_EDGES) return;
    int d = dst[e];
    int pos = atomicAdd(&cursor[d], 1);
    csr[rowptr[d] + pos] = src[e];
}

// ---------------- per-node gather: Kahan f32, 4-edge unroll (4-way MLP) -----------
__global__ __launch_bounds__(256) void k_gather(const float* __restrict__ feats,
                                                const int* __restrict__ rowptr,
                                                const int* __restrict__ csr,
                                                const float* __restrict__ invs,
                                                float* __restrict__ agg) {
    int node = blockIdx.x * 4 + (threadIdx.x >> 6);
    if (node >= N_NODES) return;
    int lane = threadIdx.x & 63;
    int beg = rowptr[node], end = rowptr[node + 1];
    float wd = invs[node];
    float sx = 0.f, cx = 0.f, sy = 0.f, cy = 0.f;
    int i = beg;
    for (; i + 4 <= end; i += 4) {
        int s0 = csr[i], s1 = csr[i + 1], s2 = csr[i + 2], s3 = csr[i + 3];
        float n0 = invs[s0] * wd, n1 = invs[s1] * wd;
        float n2 = invs[s2] * wd, n3 = invs[s3] * wd;
        float2 f0 = ((const float2*)(feats + (size_t)s0 * D))[lane];
        float2 f1 = ((const float2*)(feats + (size_t)s1 * D))[lane];
        float2 f2 = ((const float2*)(feats + (size_t)s2 * D))[lane];
        float2 f3 = ((const float2*)(feats + (size_t)s3 * D))[lane];
        KAH(sx, cx, n0 * f0.x); KAH(sy, cy, n0 * f0.y);
        KAH(sx, cx, n1 * f1.x); KAH(sy, cy, n1 * f1.y);
        KAH(sx, cx, n2 * f2.x); KAH(sy, cy, n2 * f2.y);
        KAH(sx, cx, n3 * f3.x); KAH(sy, cy, n3 * f3.y);
    }
    for (; i < end; i++) {
        int s = csr[i];
        float nrm = invs[s] * wd;
        float2 f = ((const float2*)(feats + (size_t)s * D))[lane];
        KAH(sx, cx, nrm * f.x);
        KAH(sy, cy, nrm * f.y);
    }
    ((float2*)(agg + (size_t)node * D))[lane] = make_float2(sx, sy);
}

// ---------------- W_conv split: f32 -> (hi,lo) bf16 fragments ----------------------
__global__ __launch_bounds__(256) void k_wcsplit(const float* __restrict__ W,
                                                 unsigned short* __restrict__ whi,
                                                 unsigned short* __restrict__ wlo) {
    int u = blockIdx.x * 256 + threadIdx.x;   // 0..2047
    int lhi = u & 3, c = (u >> 2) & 127, ks = u >> 9;
    int k0 = ks * 32 + lhi * 8;
    unsigned short vh[8] __attribute__((aligned(16)));
    unsigned short vl[8] __attribute__((aligned(16)));
#pragma unroll
    for (int j = 0; j < 8; j++) {
        float x = W[(size_t)(k0 + j) * D + c];
        unsigned short h = f2bf(x);
        vh[j] = h;
        vl[j] = f2bf(x - bf2f(h));
    }
    *(int4*)(whi + (size_t)u * 8) = *(int4*)vh;
    *(int4*)(wlo + (size_t)u * 8) = *(int4*)vl;
}

// ---------------- gate_W split: f32 [128][64] -> (hi,lo) fragments -----------------
__global__ __launch_bounds__(256) void k_wgsplit(const float* __restrict__ gW,
                                                 unsigned short* __restrict__ ghi,
                                                 unsigned short* __restrict__ glo) {
    int u = blockIdx.x * 256 + threadIdx.x;   // 0..1023
    int lhi = u & 3, e = (u >> 2) & 63, ks = u >> 8;
    int k0 = ks * 32 + lhi * 8;
    unsigned short vh[8] __attribute__((aligned(16)));
    unsigned short vl[8] __attribute__((aligned(16)));
#pragma unroll
    for (int j = 0; j < 8; j++) {
        float x = gW[(size_t)(k0 + j) * NE + e];
        unsigned short h = f2bf(x);
        vh[j] = h;
        vl[j] = f2bf(x - bf2f(h));
    }
    *(int4*)(ghi + (size_t)u * 8) = *(int4*)vh;
    *(int4*)(glo + (size_t)u * 8) = *(int4*)vl;
}

// ---------------- fused conv GEMM + gate (split-bf16 MFMA, f32-class error) --------
__global__ __launch_bounds__(512, 4) void k_convgate(
        const float* __restrict__ agg,
        const unsigned short* __restrict__ whi, const unsigned short* __restrict__ wlo,
        const float* __restrict__ bias,
        const unsigned short* __restrict__ ghi, const unsigned short* __restrict__ glo,
        const float* __restrict__ gb,
        float* __restrict__ out, float* __restrict__ gwout, int* __restrict__ topi,
        int* __restrict__ rcnt, int* __restrict__ redo) {
    __shared__ __align__(16) char smem[32768];  // XH 8K | XL 8K | YB 16K (SC = YB, after out store)
    const int XH = 0, XL = 8192, YB = 16384, SC = 16384;
    int r0 = blockIdx.x * TILE_R;
    int rows = min(TILE_R, N_NODES - r0);
    int tid = threadIdx.x;
    int wv = tid >> 6, lane = tid & 63;
    int lhi = lane >> 4, llo = lane & 15;
    int sr = tid >> 4, ss = tid & 15;
    f32x4 zero = {0.f, 0.f, 0.f, 0.f};

    // conv W fragments: wave wv owns out-cols c = wv*16+llo
    int c = wv * 16 + llo;
    s16x8 whf[4], wlf[4];
#pragma unroll
    for (int ks = 0; ks < 4; ks++) {
        size_t u = ((size_t)(ks * 128 + c) * 4 + lhi) * 8;
        whf[ks] = *(const s16x8*)(whi + u);
        wlf[ks] = *(const s16x8*)(wlo + u);
    }
    // gate W fragments (waves 0-3 only): expert e = wv*16+llo
    s16x8 gwh[4], gwl[4];
    if (wv < 4) {
#pragma unroll
        for (int ks = 0; ks < 4; ks++) {
            size_t u = ((size_t)(ks * 64 + c) * 4 + lhi) * 8;
            gwh[ks] = *(const s16x8*)(ghi + u);
            gwl[ks] = *(const s16x8*)(glo + u);
        }
    }

    // stage X hi/lo
    {
        float v[8];
        if (sr < rows) {
            const float4* xr = (const float4*)(agg + (size_t)(r0 + sr) * D + ss * 8);
            *(float4*)(v + 0) = xr[0];
            *(float4*)(v + 4) = xr[1];
        } else {
#pragma unroll
            for (int k = 0; k < 8; k++) v[k] = 0.f;
        }
        unsigned short hb[8] __attribute__((aligned(16)));
        unsigned short lb[8] __attribute__((aligned(16)));
#pragma unroll
        for (int k = 0; k < 8; k++) {
            unsigned short h = f2bf(v[k]);
            hb[k] = h;
            lb[k] = f2bf(v[k] - bf2f(h));
        }
        int swz = (sr & 7) << 4;
        *(int4*)(smem + XH + sr * 256 + ((ss * 16) ^ swz)) = *(int4*)hb;
        *(int4*)(smem + XL + sr * 256 + ((ss * 16) ^ swz)) = *(int4*)lb;
    }
    __syncthreads();   // (1) X staged

    // conv GEMM: x*w ~= xh*wh + xh*wl + xl*wh
    f32x4 acc[2];
    acc[0] = zero; acc[1] = zero;
#pragma unroll
    for (int ks = 0; ks < 4; ks++) {
        int kb = ks * 64 + lhi * 16;
        int sw0 = (llo & 7) << 4;
        s16x8 ah0 = *(const s16x8*)(smem + XH + llo * 256        + (kb ^ sw0));
        s16x8 ah1 = *(const s16x8*)(smem + XH + (llo + 16) * 256 + (kb ^ sw0));
        s16x8 al0 = *(const s16x8*)(smem + XL + llo * 256        + (kb ^ sw0));
        s16x8 al1 = *(const s16x8*)(smem + XL + (llo + 16) * 256 + (kb ^ sw0));
        acc[0] = __builtin_amdgcn_mfma_f32_16x16x32_bf16(ah0, whf[ks], acc[0], 0, 0, 0);
        acc[0] = __builtin_amdgcn_mfma_f32_16x16x32_bf16(ah0, wlf[ks], acc[0], 0, 0, 0);
        acc[0] = __builtin_amdgcn_mfma_f32_16x16x32_bf16(al0, whf[ks], acc[0], 0, 0, 0);
        acc[1] = __builtin_amdgcn_mfma_f32_16x16x32_bf16(ah1, whf[ks], acc[1], 0, 0, 0);
        acc[1] = __builtin_amdgcn_mfma_f32_16x16x32_bf16(ah1, wlf[ks], acc[1], 0, 0, 0);
        acc[1] = __builtin_amdgcn_mfma_f32_16x16x32_bf16(al1, whf[ks], acc[1], 0, 0, 0);  // r20 bug: was wlf
    }
    __syncthreads();   // (2) all XH/XL reads done -> safe to overwrite

    // out-tile -> YB (f32) and hi/lo split -> XH/XL (element (m,c))
    {
        float bb = bias[c];
#pragma unroll
        for (int mt = 0; mt < 2; mt++)
#pragma unroll
            for (int r = 0; r < 4; r++) {
                int m = mt * 16 + lhi * 4 + r;
                float ov = acc[mt][r] + bb;
                int swz = (m & 7) << 4;
                *(float*)(smem + YB + m * 512 + ((c * 4) ^ swz)) = ov;
                unsigned short h = f2bf(ov);
                *(unsigned short*)(smem + XH + m * 256 + ((c * 2) ^ swz)) = h;
                *(unsigned short*)(smem + XL + m * 256 + ((c * 2) ^ swz)) = f2bf(ov - bf2f(h));
            }
    }
    __syncthreads();   // (3) YB + out-hi/lo ready

    // store out (coalesced) ; gate GEMM (waves 0-3)
    if (sr < rows) {
        int swz = (sr & 7) << 4;
        int4 a = *(const int4*)(smem + YB + sr * 512 + ((ss * 32) ^ swz));
        int4 b = *(const int4*)(smem + YB + sr * 512 + ((ss * 32 + 16) ^ swz));
        float4* op = (float4*)(out + (size_t)(r0 + sr) * D + ss * 8);
        op[0] = *(float4*)&a;
        op[1] = *(float4*)&b;
    }
    f32x4 accg[2];
    accg[0] = zero; accg[1] = zero;
    if (wv < 4) {
#pragma unroll
        for (int ks = 0; ks < 4; ks++) {
            int kb = ks * 64 + lhi * 16;
            int sw0 = (llo & 7) << 4;
            s16x8 ah0 = *(const s16x8*)(smem + XH + llo * 256        + (kb ^ sw0));
            s16x8 ah1 = *(const s16x8*)(smem + XH + (llo + 16) * 256 + (kb ^ sw0));
            s16x8 al0 = *(const s16x8*)(smem + XL + llo * 256        + (kb ^ sw0));
            s16x8 al1 = *(const s16x8*)(smem + XL + (llo + 16) * 256 + (kb ^ sw0));
            accg[0] = __builtin_amdgcn_mfma_f32_16x16x32_bf16(ah0, gwh[ks], accg[0], 0, 0, 0);
            accg[0] = __builtin_amdgcn_mfma_f32_16x16x32_bf16(ah0, gwl[ks], accg[0], 0, 0, 0);
            accg[0] = __builtin_amdgcn_mfma_f32_16x16x32_bf16(al0, gwh[ks], accg[0], 0, 0, 0);
            accg[1] = __builtin_amdgcn_mfma_f32_16x16x32_bf16(ah1, gwh[ks], accg[1], 0, 0, 0);
            accg[1] = __builtin_amdgcn_mfma_f32_16x16x32_bf16(ah1, gwl[ks], accg[1], 0, 0, 0);
            accg[1] = __builtin_amdgcn_mfma_f32_16x16x32_bf16(al1, gwh[ks], accg[1], 0, 0, 0);
        }
    }
    __syncthreads();   // (4) YB reads (out store) done -> SC region free

    if (wv < 4) {
        float gbe = gb[c];
#pragma unroll
        for (int mt = 0; mt < 2; mt++)
#pragma unroll
            for (int r = 0; r < 4; r++) {
                int m = mt * 16 + lhi * 4 + r;
                *(float*)(smem + SC + m * 256 + c * 4) = accg[mt][r] + gbe;
            }
    }
    __syncthreads();   // (5) SC ready

    // top-2 / top-3 + gap test: wave wv owns tokens [wv*4, +4), lane = expert
    const float TAU = 2e-4f;
#pragma unroll
    for (int j = 0; j < 4; j++) {
        int tt = wv * 4 + j;
        if (tt >= rows) break;
        int t = r0 + tt;
        float sf = *(const float*)(smem + SC + tt * 256 + lane * 4);

        float v1 = sf; int i1 = lane;
#pragma unroll
        for (int off = 32; off; off >>= 1) {
            float ov = __shfl_xor(v1, off);
            int   oi = __shfl_xor(i1, off);
            if (ov > v1 || (ov == v1 && oi < i1)) { v1 = ov; i1 = oi; }
        }
        float v2 = (lane == i1) ? -INFINITY : sf; int i2 = lane;
#pragma unroll
        for (int off = 32; off; off >>= 1) {
            float ov = __shfl_xor(v2, off);
            int   oi = __shfl_xor(i2, off);
            if (ov > v2 || (ov == v2 && oi < i2)) { v2 = ov; i2 = oi; }
        }
        float v3 = (lane == i1 || lane == i2) ? -INFINITY : sf;
#pragma unroll
        for (int off = 32; off; off >>= 1)
            v3 = fmaxf(v3, __shfl_xor(v3, off));

        if (lane == 0) {
            float dd = v2 - v1;
            float e2 = expf(dd);
            float g0 = 1.0f / (1.0f + e2);
            gwout[2 * t] = g0;
            gwout[2 * t + 1] = e2 * g0;
            topi[2 * t] = i1;
            topi[2 * t + 1] = i2;
            if ((v1 - v2 <= TAU) || (v2 - v3 <= TAU)) {
                int slot = atomicAdd(rcnt, 1);
                redo[slot] = t;
            }
        }
    }
}

// ---------------- gate FIX: comp-f32 rescore of ambiguous tokens (rare) ------------
__global__ __launch_bounds__(256) void k_gfix(const float* __restrict__ nf,
                                              const float* __restrict__ gW,
                                              const float* __restrict__ gb,
                                              const int* __restrict__ rcnt,
                                              const int* __restrict__ redo,
                                              float* __restrict__ gwout,
                                              int* __restrict__ topi) {
    int nredo = *rcnt;
    int lane = threadIdx.x & 63;
    int widx = blockIdx.x * 4 + (threadIdx.x >> 6);
    float gbf = gb[lane];
    for (int i = widx; i < nredo; i += gridDim.x * 4) {
        int t = redo[i];
        const float* xr = nf + (size_t)t * D;
        float s = 0.f, c = 0.f;
        for (int k = 0; k < D; k++)
            DOT2(s, c, xr[k], gW[k * NE + lane]);
        TSUM(s, c, gbf);
        float vv = s + c, rr = (s - vv) + c;

        float a1v = vv, a1r = rr; int i1 = lane;
#pragma unroll
        for (int off = 32; off; off >>= 1) {
            float ov = __shfl_xor(a1v, off);
            float orr = __shfl_xor(a1r, off);
            int   oi = __shfl_xor(i1, off);
            bool gt = (ov > a1v) || (ov == a1v && (orr > a1r || (orr == a1r && oi < i1)));
            if (gt) { a1v = ov; a1r = orr; i1 = oi; }
        }
        bool ex = (lane == i1);
        float a2v = ex ? -INFINITY : vv;
        float a2r = ex ? 0.f : rr;
        int i2 = lane;
#pragma unroll
        for (int off = 32; off; off >>= 1) {
            float ov = __shfl_xor(a2v, off);
            float orr = __shfl_xor(a2r, off);
            int   oi = __shfl_xor(i2, off);
            bool gt = (ov > a2v) || (ov == a2v && (orr > a2r || (orr == a2r && oi < i2)));
            if (gt) { a2v = ov; a2r = orr; i2 = oi; }
        }

        if (lane == 0) {
            float dd = (a2v - a1v) + (a2r - a1r);
            float e2 = expf(dd);
            float g0 = 1.0f / (1.0f + e2);
            gwout[2 * t] = g0;
            gwout[2 * t + 1] = e2 * g0;
            topi[2 * t] = i1;
            topi[2 * t + 1] = i2;
        }
    }
}

// ---------------- dispatch: parallel two-level counting scatter ----------------
__global__ __launch_bounds__(1024) void k_disp(const int* __restrict__ topi,
                                               int* __restrict__ cnt,
                                               int* __restrict__ plist) {
    __shared__ int lcnt[NE];
    __shared__ int lbase[NE];
    int tid = threadIdx.x;
    if (tid < NE) lcnt[tid] = 0;
    __syncthreads();
    int p = blockIdx.x * 1024 + tid;
    int e = 0, lr = 0;
    bool act = (p < NPAIR);
    if (act) {
        e = topi[p];
        lr = atomicAdd(&lcnt[e], 1);
    }
    __syncthreads();
    if (tid < NE) {
        int n = lcnt[tid];
        lbase[tid] = n ? atomicAdd(&cnt[tid], n) : 0;
    }
    __syncthreads();
    if (act) {
        int slot = lbase[e] + lr;
        if (slot < CAP) plist[e * CAP + slot] = p;
    }
}

// ---------------- weight convert: f32 -> bf16 fragments, LINEAR layout -------------
__global__ __launch_bounds__(256) void k_wconv(const float* __restrict__ W1,
                                               const float* __restrict__ W2,
                                               unsigned short* __restrict__ w1c,
                                               unsigned short* __restrict__ w2c) {
    int gid = blockIdx.x * 256 + threadIdx.x;
    const int NW1 = NE * 4 * 256 * 4;            // 262144
    if (gid < NW1) {
        int lhi = gid & 3, h = (gid >> 2) & 255, ks = (gid >> 10) & 3, e = gid >> 12;
        int d0 = ks * 32 + lhi * 8;
        unsigned short v[8] __attribute__((aligned(16)));
#pragma unroll
        for (int j = 0; j < 8; j++)
            v[j] = f2bf(W1[((size_t)e * D + d0 + j) * H + h]);
        *(int4*)(w1c + (size_t)gid * 8) = *(int4*)v;
    } else {
        int g = gid - NW1;
        int lhi = g & 3, d = (g >> 2) & 127, ks = (g >> 9) & 7, e = g >> 12;
        int h0 = ks * 32 + lhi * 8;
        unsigned short v[8] __attribute__((aligned(16)));
#pragma unroll
        for (int j = 0; j < 8; j++)
            v[j] = f2bf(W2[((size_t)e * H + h0 + j) * D + d]);
        *(int4*)(w2c + (size_t)g * 8) = *(int4*)v;
    }
}

// ---------------- MoE FFN v10: 2 barriers/tile, depth-2 prefetch, reg-W ------------
__global__ __launch_bounds__(512, 4) void k_moe(const float* __restrict__ nf,
                                                const int* __restrict__ cnt,
                                                const int* __restrict__ plist,
                                                const unsigned short* __restrict__ w1c,
                                                const float* __restrict__ b1,
                                                const unsigned short* __restrict__ w2c,
                                                const float* __restrict__ b2,
                                                const float* __restrict__ gwbuf,
                                                unsigned short* __restrict__ ybuf) {
    __shared__ __align__(16) char smem[32768];
    const int XA = 0, HL = 8192, YB = 24576;
    int e = blockIdx.x & 63;         // same-expert blocks on same XCD (L2 W reuse)
    int q = blockIdx.x >> 6;
    int n = min(cnt[e], CAP);
    int ntile = (n + TILE_R - 1) / TILE_R;
    if (q >= ntile) return;
    int tid = threadIdx.x;

    int wv = tid >> 6, lane = tid & 63;
    int lhi = lane >> 4, llo = lane & 15;
    int sr = tid >> 4, ss = tid & 15;   // staging role: row, 16B-chunk
    f32x4 zero = {0.f, 0.f, 0.f, 0.f};

    // ---- load W fragments into registers (once per block; coalesced 1KB/wave) ----
    s16x8 w1f[4][2];
#pragma unroll
    for (int ks = 0; ks < 4; ks++)
#pragma unroll
        for (int nt = 0; nt < 2; nt++) {
            int h = wv * 32 + nt * 16 + llo;
            w1f[ks][nt] = *(const s16x8*)(w1c +
                ((size_t)e * 4096 + (ks * 256 + h) * 4 + lhi) * 8);
        }
    s16x8 w2f[8];
    {
        int d = wv * 16 + llo;
#pragma unroll
        for (int ks = 0; ks < 8; ks++)
            w2f[ks] = *(const s16x8*)(w2c +
                ((size_t)e * 4096 + (ks * 128 + d) * 4 + lhi) * 8);
    }

    float vals[8];
    auto loadt = [&](int rt2, float* v) {
        bool ok = false;
        if (rt2 < ntile) {
            int rows2 = min(TILE_R, n - rt2 * TILE_R);
            if (sr < rows2) {
                int p = plist[e * CAP + rt2 * TILE_R + sr];
                const float4* xr = (const float4*)(nf + (size_t)(p >> 1) * D + ss * 8);
                *(float4*)(v + 0) = xr[0];
                *(float4*)(v + 4) = xr[1];
                ok = true;
            }
        }
        if (!ok) {
#pragma unroll
            for (int k = 0; k < 8; k++) v[k] = 0.f;
        }
    };
    auto stageXA = [&]() {
        unsigned short hb[8] __attribute__((aligned(16)));
#pragma unroll
        for (int k = 0; k < 8; k++) hb[k] = f2bf(vals[k]);
        *(int4*)(smem + XA + sr * 256 + ((ss * 16) ^ ((sr & 7) << 4))) = *(int4*)hb;
    };

    // prologue: XA(t0) staged; vals holds t1
    loadt(q, vals);
    stageXA();
    loadt(q + BQ, vals);
    __syncthreads();   // XA(t0) ready

    for (int rt = q; rt < ntile; rt += BQ) {
        int r0 = rt * TILE_R;
        int rows = min(TILE_R, n - r0);

        // ---- GEMM1: H[32x256] = X @ W1; wave wv owns h-cols [wv*32, +32) ----
        f32x4 acc1[2][2];
#pragma unroll
        for (int mt = 0; mt < 2; mt++)
#pragma unroll
            for (int nt = 0; nt < 2; nt++) acc1[mt][nt] = zero;
#pragma unroll
        for (int ks = 0; ks < 4; ks++) {
            int kb = ks * 64 + lhi * 16;
            s16x8 a0 = *(const s16x8*)(smem + XA + llo * 256        + (kb ^ ((llo & 7) << 4)));
            s16x8 a1 = *(const s16x8*)(smem + XA + (llo + 16) * 256 + (kb ^ ((llo & 7) << 4)));
#pragma unroll
            for (int nt = 0; nt < 2; nt++) {
                acc1[0][nt] = __builtin_amdgcn_mfma_f32_16x16x32_bf16(a0, w1f[ks][nt], acc1[0][nt], 0, 0, 0);
                acc1[1][nt] = __builtin_amdgcn_mfma_f32_16x16x32_bf16(a1, w1f[ks][nt], acc1[1][nt], 0, 0, 0);
            }
        }

        // ---- fast gelu -> HL (bf16, swizzled) ----
#pragma unroll
        for (int mt = 0; mt < 2; mt++)
#pragma unroll
            for (int nt = 0; nt < 2; nt++)
#pragma unroll
                for (int r = 0; r < 4; r++) {
                    int m = mt * 16 + lhi * 4 + r;
                    int hc = wv * 32 + nt * 16 + llo;
                    float hv = acc1[mt][nt][r] + b1[e * H + hc];
                    *(unsigned short*)(smem + HL + m * 512 + ((hc * 2) ^ ((m & 7) << 4))) =
                        f2bf(gelu_f(hv));
                }
        __syncthreads();   // HL ready; all XA(rt) reads done

        // ---- stage XA(rt+BQ) from vals (overlaps GEMM2); issue load rt+2*BQ ----
        stageXA();
        loadt(rt + 2 * BQ, vals);

        // ---- GEMM2: Y[32x128] = H @ W2; wave wv owns d-cols [wv*16, +16) ----
        f32x4 acc2[2];
        acc2[0] = zero; acc2[1] = zero;
#pragma unroll
        for (int ks = 0; ks < 8; ks++) {
            int kb = ks * 64 + lhi * 16;
            s16x8 a0 = *(const s16x8*)(smem + HL + llo * 512        + (kb ^ ((llo & 7) << 4)));
            s16x8 a1 = *(const s16x8*)(smem + HL + (llo + 16) * 512 + (kb ^ ((llo & 7) << 4)));
            acc2[0] = __builtin_amdgcn_mfma_f32_16x16x32_bf16(a0, w2f[ks], acc2[0], 0, 0, 0);
            acc2[1] = __builtin_amdgcn_mfma_f32_16x16x32_bf16(a1, w2f[ks], acc2[1], 0, 0, 0);
        }

        // ---- stage y (acc2 + b2) into YB (bf16, swizzled) ----
        {
            int d = wv * 16 + llo;
            float bb = b2[e * D + d];
#pragma unroll
            for (int mt = 0; mt < 2; mt++)
#pragma unroll
                for (int r = 0; r < 4; r++) {
                    int m = mt * 16 + lhi * 4 + r;
                    *(unsigned short*)(smem + YB + m * 256 + ((d * 2) ^ ((m & 7) << 4))) =
                        f2bf(acc2[mt][r] + bb);
                }
        }
        __syncthreads();   // YB ready; XA(rt+BQ) ready; HL reads done

        // ---- coalesced ybuf write: thread owns (row sr, 16B chunk ss) ----
        if (sr < rows) {
            int p = plist[e * CAP + r0 + sr];
            float gw = gwbuf[p];
            unsigned short yv[8] __attribute__((aligned(16)));
            *(int4*)yv = *(const int4*)(smem + YB + sr * 256 + ((ss * 16) ^ ((sr & 7) << 4)));
#pragma unroll
            for (int k = 0; k < 8; k++) yv[k] = f2bf(gw * bf2f(yv[k]));
            *(int4*)(ybuf + (size_t)p * D + ss * 8) = *(int4*)yv;
        }
    }
}

// ---------------- BatchNorm: bnpart also writes z = nf + y0 + y1 into nf (in place) --
__global__ __launch_bounds__(256) void k_bnpart(float* __restrict__ nf,
                                                const unsigned short* __restrict__ ybuf,
                                                double* __restrict__ part) {
    int blk = blockIdx.x;
    int col = threadIdx.x & 127;
    int half = threadIdx.x >> 7;
    int r0 = blk * BN_ROWS;
    int r1 = min(r0 + BN_ROWS, N_NODES);
    double s = 0.0, ss = 0.0;
    for (int r = r0 + half; r < r1; r += 2) {
        float v32 = nf[(size_t)r * D + col]
                  + bf2f(ybuf[(size_t)(2 * r) * D + col])
                  + bf2f(ybuf[(size_t)(2 * r + 1) * D + col]);
        nf[(size_t)r * D + col] = v32;        // z for bnapply (nf dead after this)
        double v = (double)v32;
        s += v; ss += v * v;
    }
    __shared__ double sh[2][256];
    sh[0][threadIdx.x] = s; sh[1][threadIdx.x] = ss;
    __syncthreads();
    if (threadIdx.x < 128) {
        part[(size_t)blk * 256 + col]       = sh[0][col] + sh[0][col + 128];
        part[(size_t)blk * 256 + 128 + col] = sh[1][col] + sh[1][col + 128];
    }
}

__global__ void k_bnstats(const double* __restrict__ part,
                          const float* __restrict__ gamma,
                          float* __restrict__ stats) {
    int col = threadIdx.x;   // 128 threads
    double s = 0.0, ss = 0.0;
    for (int b = 0; b < BN_NBLK; b++) {
        s  += part[(size_t)b * 256 + col];
        ss += part[(size_t)b * 256 + 128 + col];
    }
    double mean = s / (double)N_NODES;
    double var = ss / (double)N_NODES - mean * mean;
    stats[col] = (float)mean;
    stats[128 + col] = gamma[col] * (float)(1.0 / sqrt(var + 1e-5));
}

// ---------------- bnapply v2: in-place on z (out), float4 ----------------
__global__ __launch_bounds__(256) void k_bnapply(const float* __restrict__ stats,
                                                 const float* __restrict__ beta,
                                                 float* __restrict__ out) {
    int i = blockIdx.x * blockDim.x + threadIdx.x;   // float4 index
    if (i >= N_NODES * (D / 4)) return;
    int q = i & 31;
    int c0 = q * 4;
    float4 z = ((const float4*)out)[i];
    float4 r;
    r.x = (z.x - stats[c0 + 0]) * stats[128 + c0 + 0] + beta[c0 + 0];
    r.y = (z.y - stats[c0 + 1]) * stats[128 + c0 + 1] + beta[c0 + 1];
    r.z = (z.z - stats[c0 + 2]) * stats[128 + c0 + 2] + beta[c0 + 2];
    r.w = (z.w - stats[c0 + 3]) * stats[128 + c0 + 3] + beta[c0 + 3];
    ((float4*)out)[i] = r;
}

// ---------------- launch ----------------
extern "C" void kernel_launch(void* const* d_in, const int* in_sizes, int n_in,
                              void* d_out, int out_size, void* d_ws, size_t ws_size,
                              hipStream_t stream) {
    const float* feats   = (const float*)d_in[0];
    const int*   esrc    = (const int*)d_in[1];
    const int*   edst    = (const int*)d_in[2];
    const float* W_conv  = (const float*)d_in[3];
    const float* b_conv  = (const float*)d_in[4];
    const float* gate_W  = (const float*)d_in[5];
    const float* gate_b  = (const float*)d_in[6];
    const float* W1      = (const float*)d_in[7];
    const float* b1      = (const float*)d_in[8];
    const float* W2      = (const float*)d_in[9];
    const float* b2      = (const float*)d_in[10];
    const float* bn_g    = (const float*)d_in[11];
    const float* bn_b    = (const float*)d_in[12];
    float* out = (float*)d_out;   // doubles as new_feats / z storage

    char* ws = (char*)d_ws;
    size_t off = 0;
    auto rup = [](size_t x) { return (x + 255) & ~(size_t)255; };
    int*    deg    = (int*)   (ws + off); off += rup((size_t)N_NODES * 4);
    int*    cursor = (int*)   (ws + off); off += rup((size_t)N_NODES * 4);
    int*    cnt    = (int*)   (ws + off); off += 256;
    int*    rcnt   = (int*)   (ws + off); off += 256;
    size_t zero_bytes = off;                 // deg + cursor + cnt + rcnt (~400 KB)
    float*  invs   = (float*) (ws + off); off += rup((size_t)N_NODES * 4);
    int*    rowptr = (int*)   (ws + off); off += rup((size_t)(N_NODES + 1) * 4);
    int*    csr    = (int*)   (ws + off); off += rup((size_t)N_EDGES * 4);
    float*  gwbuf  = (float*) (ws + off); off += rup((size_t)NPAIR * 4);
    int*    topi   = (int*)   (ws + off); off += rup((size_t)NPAIR * 4);
    int*    redo   = (int*)   (ws + off); off += rup((size_t)N_NODES * 4);
    int*    plist  = (int*)   (ws + off); off += rup((size_t)NE * CAP * 4);
    double* part   = (double*)(ws + off); off += rup((size_t)BN_NBLK * 256 * 8);
    float*  stats  = (float*) (ws + off); off += 1024;
    unsigned short* w1c  = (unsigned short*)(ws + off); off += rup((size_t)NE * D * H * 2); // 4 MB
    unsigned short* w2c  = (unsigned short*)(ws + off); off += rup((size_t)NE * D * H * 2); // 4 MB
    unsigned short* wchi = (unsigned short*)(ws + off); off += rup((size_t)D * D * 2);      // 32 KB
    unsigned short* wclo = (unsigned short*)(ws + off); off += rup((size_t)D * D * 2);      // 32 KB
    unsigned short* wghi = (unsigned short*)(ws + off); off += rup((size_t)D * NE * 2);     // 16 KB
    unsigned short* wglo = (unsigned short*)(ws + off); off += rup((size_t)D * NE * 2);     // 16 KB
    unsigned short* ybuf = (unsigned short*)(ws + off); off += rup((size_t)NPAIR * D * 2);  // 25.6 MB
    float*  agg    = (float*)ybuf;   // lifetime-disjoint alias (agg dead before k_moe writes ybuf)
    (void)ws_size; (void)in_sizes; (void)n_in; (void)out_size;

    hipMemsetAsync(d_ws, 0, zero_bytes, stream);

    k_wconv<<<2 * NE * 4 * 256 * 4 / 256, 256, 0, stream>>>(W1, W2, w1c, w2c);
    k_wcsplit<<<8, 256, 0, stream>>>(W_conv, wchi, wclo);
    k_wgsplit<<<4, 256, 0, stream>>>(gate_W, wghi, wglo);
    k_deg<<<(N_EDGES + 255) / 256, 256, 0, stream>>>(edst, deg);
    k_invsqrt<<<(N_NODES + 255) / 256, 256, 0, stream>>>(deg, invs);
    k_scan<<<1, 1024, 0, stream>>>(deg, rowptr);
    k_scatter<<<(N_EDGES + 255) / 256, 256, 0, stream>>>(esrc, edst, rowptr, cursor, csr);
    k_gather<<<(N_NODES + 3) / 4, 256, 0, stream>>>(feats, rowptr, csr, invs, agg);
    k_convgate<<<(N_NODES + TILE_R - 1) / TILE_R, 512, 0, stream>>>(
        agg, wchi, wclo, b_conv, wghi, wglo, gate_b, out, gwbuf, topi, rcnt, redo);
    k_gfix<<<128, 256, 0, stream>>>(out, gate_W, gate_b, rcnt, redo, gwbuf, topi);
    k_disp<<<(NPAIR + 1023) / 1024, 1024, 0, stream>>>(topi, cnt, plist);
    k_moe<<<NE * BQ, 512, 0, stream>>>(out, cnt, plist, w1c, b1, w2c, b2, gwbuf, ybuf);
    k_bnpart<<<BN_NBLK, 256, 0, stream>>>(out, ybuf, part);
    k_bnstats<<<1, 128, 0, stream>>>(part, bn_g, stats);
    k_bnapply<<<(N_NODES * (D / 4) + 255) / 256, 256, 0, stream>>>(stats, bn_b, out);
}

// Round 23
// 401.209 us; speedup vs baseline: 1.0576x; 1.0576x over previous
//
#include <hip/hip_runtime.h>
#include <math.h>

#define N_NODES 50000
#define N_EDGES 500000
#define D 128
#define H 256
#define NE 64
#define TOPK 2
#define NPAIR (N_NODES * TOPK)
#define CAP 3126               // 2 * ceil(100000/64)
#define TILE_R 32
#define BQ 16                  // blocks per expert in k_moe (1024 blocks = 4/CU)
#define BN_NBLK 128
#define BN_ROWS ((N_NODES + BN_NBLK - 1) / BN_NBLK) // 391

typedef __attribute__((ext_vector_type(8))) short s16x8;
typedef __attribute__((ext_vector_type(4))) float f32x4;

__device__ __forceinline__ unsigned short f2bf(float f) {
    unsigned u = __float_as_uint(f);
    unsigned r = (u + 0x7fffu + ((u >> 16) & 1u)) >> 16;
    return (unsigned short)r;
}
__device__ __forceinline__ float bf2f(unsigned short u) {
    return __uint_as_float(((unsigned)u) << 16);
}

// gelu(x) = 0.5x(1+erf(x/sqrt2)); erf via A&S 7.1.26 (|err|<=1.5e-7 << bf16 quant)
__device__ __forceinline__ float gelu_f(float x) {
    float u = 0.70710678118654752f * x;
    float au = fabsf(u);
    float t = 1.0f / fmaf(0.3275911f, au, 1.0f);
    float poly = t * fmaf(t, fmaf(t, fmaf(t, fmaf(t, 1.061405429f, -1.453152027f),
                      1.421413741f), -0.284496736f), 0.254829592f);
    float e = __expf(-u * u);
    float erfa = 1.0f - poly * e;
    float erfu = copysignf(erfa, u);
    return 0.5f * x * (1.0f + erfu);
}

// Compensated f32: TwoProd (mul + fma residual) + branch-free TwoSum.
#define DOT2(s, c, xx, ww) {                      \
    float p_ = (xx) * (ww);                       \
    float e1_ = fmaf((xx), (ww), -p_);            \
    float t_ = (s) + p_;                          \
    float z_ = t_ - (s);                          \
    float e2_ = ((s) - (t_ - z_)) + (p_ - z_);    \
    (s) = t_;                                     \
    (c) += e1_ + e2_; }

#define TSUM(s, c, pp) {                          \
    float p_ = (pp);                              \
    float t_ = (s) + p_;                          \
    float z_ = t_ - (s);                          \
    float e2_ = ((s) - (t_ - z_)) + (p_ - z_);    \
    (s) = t_;                                     \
    (c) += e2_; }

// Kahan add: 4 ops; order-variation ~1e-7 rel (covered by gate TAU band)
#define KAH(s, c, pp) {                           \
    float y_ = (pp) - (c);                        \
    float t_ = (s) + y_;                          \
    (c) = (t_ - (s)) - y_;                        \
    (s) = t_; }

// ---------------- degree count ----------------
__global__ void k_deg(const int* __restrict__ dst, int* __restrict__ deg) {
    int i = blockIdx.x * blockDim.x + threadIdx.x;
    if (i < N_EDGES) atomicAdd(&deg[dst[i]], 1);
}

__global__ void k_invsqrt(const int* __restrict__ deg, float* __restrict__ invs) {
    int i = blockIdx.x * blockDim.x + threadIdx.x;
    if (i < N_NODES) {
        double d = (double)deg[i];
        if (d < 1.0) d = 1.0;
        invs[i] = (float)(1.0 / sqrt(d));
    }
}

// ---------------- exclusive scan of deg -> rowptr ----------------
__global__ __launch_bounds__(1024) void k_scan(const int* __restrict__ deg,
                                               int* __restrict__ rowptr) {
    __shared__ int sh[1024];
    int t = threadIdx.x;
    const int chunk = (N_NODES + 1023) / 1024;   // 49
    int lo = t * chunk;
    int hi = min(lo + chunk, N_NODES);
    int s = 0;
    for (int i = lo; i < hi; i++) s += deg[i];
    sh[t] = s;
    __syncthreads();
    for (int off = 1; off < 1024; off <<= 1) {
        int v = (t >= off) ? sh[t - off] : 0;
        __syncthreads();
        sh[t] += v;
        __syncthreads();
    }
    int run = (t == 0) ? 0 : sh[t - 1];
    for (int i = lo; i < hi; i++) { rowptr[i] = run; run += deg[i]; }
    if (t == 1023) rowptr[N_NODES] = run;
}

// ---------------- scatter edges into CSR ----------------
__global__ void k_scatter(const int* __restrict__ src, const int* __restrict__ dst,
                          const int* __restrict__ rowptr, int* __restrict__ cursor,
                          int* __restrict__ csr) {
    int e = blockIdx.x * blockDim.x + threadIdx.x;
    if (e >= N_EDGES) return;
    int d = dst[e];
    int pos = atomicAdd(&cursor[d], 1);
    csr[rowptr[d] + pos] = src[e];
}

// ---------------- per-node gather: Kahan f32, 4-edge unroll (4-way MLP) -----------
__global__ __launch_bounds__(256) void k_gather(const float* __restrict__ feats,
                                                const int* __restrict__ rowptr,
                                                const int* __restrict__ csr,
                                                const float* __restrict__ invs,
                                                float* __restrict__ agg) {
    int node = blockIdx.x * 4 + (threadIdx.x >> 6);
    if (node >= N_NODES) return;
    int lane = threadIdx.x & 63;
    int beg = rowptr[node], end = rowptr[node + 1];
    float wd = invs[node];
    float sx = 0.f, cx = 0.f, sy = 0.f, cy = 0.f;
    int i = beg;
    for (; i + 4 <= end; i += 4) {
        int s0 = csr[i], s1 = csr[i + 1], s2 = csr[i + 2], s3 = csr[i + 3];
        float n0 = invs[s0] * wd, n1 = invs[s1] * wd;
        float n2 = invs[s2] * wd, n3 = invs[s3] * wd;
        float2 f0 = ((const float2*)(feats + (size_t)s0 * D))[lane];
        float2 f1 = ((const float2*)(feats + (size_t)s1 * D))[lane];
        float2 f2 = ((const float2*)(feats + (size_t)s2 * D))[lane];
        float2 f3 = ((const float2*)(feats + (size_t)s3 * D))[lane];
        KAH(sx, cx, n0 * f0.x); KAH(sy, cy, n0 * f0.y);
        KAH(sx, cx, n1 * f1.x); KAH(sy, cy, n1 * f1.y);
        KAH(sx, cx, n2 * f2.x); KAH(sy, cy, n2 * f2.y);
        KAH(sx, cx, n3 * f3.x); KAH(sy, cy, n3 * f3.y);
    }
    for (; i < end; i++) {
        int s = csr[i];
        float nrm = invs[s] * wd;
        float2 f = ((const float2*)(feats + (size_t)s * D))[lane];
        KAH(sx, cx, nrm * f.x);
        KAH(sy, cy, nrm * f.y);
    }
    ((float2*)(agg + (size_t)node * D))[lane] = make_float2(sx, sy);
}

// ---------------- W_conv split: f32 -> (hi,lo) bf16 fragments ----------------------
__global__ __launch_bounds__(256) void k_wcsplit(const float* __restrict__ W,
                                                 unsigned short* __restrict__ whi,
                                                 unsigned short* __restrict__ wlo) {
    int u = blockIdx.x * 256 + threadIdx.x;   // 0..2047
    int lhi = u & 3, c = (u >> 2) & 127, ks = u >> 9;
    int k0 = ks * 32 + lhi * 8;
    unsigned short vh[8] __attribute__((aligned(16)));
    unsigned short vl[8] __attribute__((aligned(16)));
#pragma unroll
    for (int j = 0; j < 8; j++) {
        float x = W[(size_t)(k0 + j) * D + c];
        unsigned short h = f2bf(x);
        vh[j] = h;
        vl[j] = f2bf(x - bf2f(h));
    }
    *(int4*)(whi + (size_t)u * 8) = *(int4*)vh;
    *(int4*)(wlo + (size_t)u * 8) = *(int4*)vl;
}

// ---------------- gate_W split: f32 [128][64] -> (hi,lo) fragments -----------------
__global__ __launch_bounds__(256) void k_wgsplit(const float* __restrict__ gW,
                                                 unsigned short* __restrict__ ghi,
                                                 unsigned short* __restrict__ glo) {
    int u = blockIdx.x * 256 + threadIdx.x;   // 0..1023
    int lhi = u & 3, e = (u >> 2) & 63, ks = u >> 8;
    int k0 = ks * 32 + lhi * 8;
    unsigned short vh[8] __attribute__((aligned(16)));
    unsigned short vl[8] __attribute__((aligned(16)));
#pragma unroll
    for (int j = 0; j < 8; j++) {
        float x = gW[(size_t)(k0 + j) * NE + e];
        unsigned short h = f2bf(x);
        vh[j] = h;
        vl[j] = f2bf(x - bf2f(h));
    }
    *(int4*)(ghi + (size_t)u * 8) = *(int4*)vh;
    *(int4*)(glo + (size_t)u * 8) = *(int4*)vl;
}

// ---------------- fused conv GEMM + gate (split-bf16 MFMA, f32-class error) --------
__global__ __launch_bounds__(512, 4) void k_convgate(
        const float* __restrict__ agg,
        const unsigned short* __restrict__ whi, const unsigned short* __restrict__ wlo,
        const float* __restrict__ bias,
        const unsigned short* __restrict__ ghi, const unsigned short* __restrict__ glo,
        const float* __restrict__ gb,
        float* __restrict__ out, float* __restrict__ gwout, int* __restrict__ topi,
        int* __restrict__ rcnt, int* __restrict__ redo) {
    __shared__ __align__(16) char smem[32768];  // XH 8K | XL 8K | YB 16K (SC = YB, after out store)
    const int XH = 0, XL = 8192, YB = 16384, SC = 16384;
    int r0 = blockIdx.x * TILE_R;
    int rows = min(TILE_R, N_NODES - r0);
    int tid = threadIdx.x;
    int wv = tid >> 6, lane = tid & 63;
    int lhi = lane >> 4, llo = lane & 15;
    int sr = tid >> 4, ss = tid & 15;
    f32x4 zero = {0.f, 0.f, 0.f, 0.f};

    // conv W fragments: wave wv owns out-cols c = wv*16+llo
    int c = wv * 16 + llo;
    s16x8 whf[4], wlf[4];
#pragma unroll
    for (int ks = 0; ks < 4; ks++) {
        size_t u = ((size_t)(ks * 128 + c) * 4 + lhi) * 8;
        whf[ks] = *(const s16x8*)(whi + u);
        wlf[ks] = *(const s16x8*)(wlo + u);
    }
    // gate W fragments (waves 0-3 only): expert e = wv*16+llo
    s16x8 gwh[4], gwl[4];
    if (wv < 4) {
#pragma unroll
        for (int ks = 0; ks < 4; ks++) {
            size_t u = ((size_t)(ks * 64 + c) * 4 + lhi) * 8;
            gwh[ks] = *(const s16x8*)(ghi + u);
            gwl[ks] = *(const s16x8*)(glo + u);
        }
    }

    // stage X hi/lo
    {
        float v[8];
        if (sr < rows) {
            const float4* xr = (const float4*)(agg + (size_t)(r0 + sr) * D + ss * 8);
            *(float4*)(v + 0) = xr[0];
            *(float4*)(v + 4) = xr[1];
        } else {
#pragma unroll
            for (int k = 0; k < 8; k++) v[k] = 0.f;
        }
        unsigned short hb[8] __attribute__((aligned(16)));
        unsigned short lb[8] __attribute__((aligned(16)));
#pragma unroll
        for (int k = 0; k < 8; k++) {
            unsigned short h = f2bf(v[k]);
            hb[k] = h;
            lb[k] = f2bf(v[k] - bf2f(h));
        }
        int swz = (sr & 7) << 4;
        *(int4*)(smem + XH + sr * 256 + ((ss * 16) ^ swz)) = *(int4*)hb;
        *(int4*)(smem + XL + sr * 256 + ((ss * 16) ^ swz)) = *(int4*)lb;
    }
    __syncthreads();   // (1) X staged

    // conv GEMM: x*w ~= xh*wh + xh*wl + xl*wh
    f32x4 acc[2];
    acc[0] = zero; acc[1] = zero;
#pragma unroll
    for (int ks = 0; ks < 4; ks++) {
        int kb = ks * 64 + lhi * 16;
        int sw0 = (llo & 7) << 4;
        s16x8 ah0 = *(const s16x8*)(smem + XH + llo * 256        + (kb ^ sw0));
        s16x8 ah1 = *(const s16x8*)(smem + XH + (llo + 16) * 256 + (kb ^ sw0));
        s16x8 al0 = *(const s16x8*)(smem + XL + llo * 256        + (kb ^ sw0));
        s16x8 al1 = *(const s16x8*)(smem + XL + (llo + 16) * 256 + (kb ^ sw0));
        acc[0] = __builtin_amdgcn_mfma_f32_16x16x32_bf16(ah0, whf[ks], acc[0], 0, 0, 0);
        acc[0] = __builtin_amdgcn_mfma_f32_16x16x32_bf16(ah0, wlf[ks], acc[0], 0, 0, 0);
        acc[0] = __builtin_amdgcn_mfma_f32_16x16x32_bf16(al0, whf[ks], acc[0], 0, 0, 0);
        acc[1] = __builtin_amdgcn_mfma_f32_16x16x32_bf16(ah1, whf[ks], acc[1], 0, 0, 0);
        acc[1] = __builtin_amdgcn_mfma_f32_16x16x32_bf16(ah1, wlf[ks], acc[1], 0, 0, 0);
        acc[1] = __builtin_amdgcn_mfma_f32_16x16x32_bf16(al1, whf[ks], acc[1], 0, 0, 0);
    }
    __syncthreads();   // (2) all XH/XL reads done -> safe to overwrite

    // out-tile -> YB (f32) and hi/lo split -> XH/XL (element (m,c))
    {
        float bb = bias[c];
#pragma unroll
        for (int mt = 0; mt < 2; mt++)
#pragma unroll
            for (int r = 0; r < 4; r++) {
                int m = mt * 16 + lhi * 4 + r;
                float ov = acc[mt][r] + bb;
                int swz = (m & 7) << 4;
                *(float*)(smem + YB + m * 512 + ((c * 4) ^ swz)) = ov;
                unsigned short h = f2bf(ov);
                *(unsigned short*)(smem + XH + m * 256 + ((c * 2) ^ swz)) = h;
                *(unsigned short*)(smem + XL + m * 256 + ((c * 2) ^ swz)) = f2bf(ov - bf2f(h));
            }
    }
    __syncthreads();   // (3) YB + out-hi/lo ready

    // store out (coalesced) ; gate GEMM (waves 0-3)
    if (sr < rows) {
        int swz = (sr & 7) << 4;
        int4 a = *(const int4*)(smem + YB + sr * 512 + ((ss * 32) ^ swz));
        int4 b = *(const int4*)(smem + YB + sr * 512 + ((ss * 32 + 16) ^ swz));
        float4* op = (float4*)(out + (size_t)(r0 + sr) * D + ss * 8);
        op[0] = *(float4*)&a;
        op[1] = *(float4*)&b;
    }
    f32x4 accg[2];
    accg[0] = zero; accg[1] = zero;
    if (wv < 4) {
#pragma unroll
        for (int ks = 0; ks < 4; ks++) {
            int kb = ks * 64 + lhi * 16;
            int sw0 = (llo & 7) << 4;
            s16x8 ah0 = *(const s16x8*)(smem + XH + llo * 256        + (kb ^ sw0));
            s16x8 ah1 = *(const s16x8*)(smem + XH + (llo + 16) * 256 + (kb ^ sw0));
            s16x8 al0 = *(const s16x8*)(smem + XL + llo * 256        + (kb ^ sw0));
            s16x8 al1 = *(const s16x8*)(smem + XL + (llo + 16) * 256 + (kb ^ sw0));
            accg[0] = __builtin_amdgcn_mfma_f32_16x16x32_bf16(ah0, gwh[ks], accg[0], 0, 0, 0);
            accg[0] = __builtin_amdgcn_mfma_f32_16x16x32_bf16(ah0, gwl[ks], accg[0], 0, 0, 0);
            accg[0] = __builtin_amdgcn_mfma_f32_16x16x32_bf16(al0, gwh[ks], accg[0], 0, 0, 0);
            accg[1] = __builtin_amdgcn_mfma_f32_16x16x32_bf16(ah1, gwh[ks], accg[1], 0, 0, 0);
            accg[1] = __builtin_amdgcn_mfma_f32_16x16x32_bf16(ah1, gwl[ks], accg[1], 0, 0, 0);
            accg[1] = __builtin_amdgcn_mfma_f32_16x16x32_bf16(al1, gwh[ks], accg[1], 0, 0, 0);
        }
    }
    __syncthreads();   // (4) YB reads (out store) done -> SC region free

    if (wv < 4) {
        float gbe = gb[c];
#pragma unroll
        for (int mt = 0; mt < 2; mt++)
#pragma unroll
            for (int r = 0; r < 4; r++) {
                int m = mt * 16 + lhi * 4 + r;
                *(float*)(smem + SC + m * 256 + c * 4) = accg[mt][r] + gbe;
            }
    }
    __syncthreads();   // (5) SC ready

    // top-2 / top-3 + gap test: wave wv owns tokens [wv*4, +4), lane = expert
    const float TAU = 2e-4f;
#pragma unroll
    for (int j = 0; j < 4; j++) {
        int tt = wv * 4 + j;
        if (tt >= rows) break;
        int t = r0 + tt;
        float sf = *(const float*)(smem + SC + tt * 256 + lane * 4);

        float v1 = sf; int i1 = lane;
#pragma unroll
        for (int off = 32; off; off >>= 1) {
            float ov = __shfl_xor(v1, off);
            int   oi = __shfl_xor(i1, off);
            if (ov > v1 || (ov == v1 && oi < i1)) { v1 = ov; i1 = oi; }
        }
        float v2 = (lane == i1) ? -INFINITY : sf; int i2 = lane;
#pragma unroll
        for (int off = 32; off; off >>= 1) {
            float ov = __shfl_xor(v2, off);
            int   oi = __shfl_xor(i2, off);
            if (ov > v2 || (ov == v2 && oi < i2)) { v2 = ov; i2 = oi; }
        }
        float v3 = (lane == i1 || lane == i2) ? -INFINITY : sf;
#pragma unroll
        for (int off = 32; off; off >>= 1)
            v3 = fmaxf(v3, __shfl_xor(v3, off));

        if (lane == 0) {
            float dd = v2 - v1;
            float e2 = expf(dd);
            float g0 = 1.0f / (1.0f + e2);
            gwout[2 * t] = g0;
            gwout[2 * t + 1] = e2 * g0;
            topi[2 * t] = i1;
            topi[2 * t + 1] = i2;
            if ((v1 - v2 <= TAU) || (v2 - v3 <= TAU)) {
                int slot = atomicAdd(rcnt, 1);
                redo[slot] = t;
            }
        }
    }
}

// ---------------- gate FIX: comp-f32 rescore of ambiguous tokens (rare) ------------
__global__ __launch_bounds__(256) void k_gfix(const float* __restrict__ nf,
                                              const float* __restrict__ gW,
                                              const float* __restrict__ gb,
                                              const int* __restrict__ rcnt,
                                              const int* __restrict__ redo,
                                              float* __restrict__ gwout,
                                              int* __restrict__ topi) {
    int nredo = *rcnt;
    int lane = threadIdx.x & 63;
    int widx = blockIdx.x * 4 + (threadIdx.x >> 6);
    float gbf = gb[lane];
    for (int i = widx; i < nredo; i += gridDim.x * 4) {
        int t = redo[i];
        const float* xr = nf + (size_t)t * D;
        float s = 0.f, c = 0.f;
        for (int k = 0; k < D; k++)
            DOT2(s, c, xr[k], gW[k * NE + lane]);
        TSUM(s, c, gbf);
        float vv = s + c, rr = (s - vv) + c;

        float a1v = vv, a1r = rr; int i1 = lane;
#pragma unroll
        for (int off = 32; off; off >>= 1) {
            float ov = __shfl_xor(a1v, off);
            float orr = __shfl_xor(a1r, off);
            int   oi = __shfl_xor(i1, off);
            bool gt = (ov > a1v) || (ov == a1v && (orr > a1r || (orr == a1r && oi < i1)));
            if (gt) { a1v = ov; a1r = orr; i1 = oi; }
        }
        bool ex = (lane == i1);
        float a2v = ex ? -INFINITY : vv;
        float a2r = ex ? 0.f : rr;
        int i2 = lane;
#pragma unroll
        for (int off = 32; off; off >>= 1) {
            float ov = __shfl_xor(a2v, off);
            float orr = __shfl_xor(a2r, off);
            int   oi = __shfl_xor(i2, off);
            bool gt = (ov > a2v) || (ov == a2v && (orr > a2r || (orr == a2r && oi < i2)));
            if (gt) { a2v = ov; a2r = orr; i2 = oi; }
        }

        if (lane == 0) {
            float dd = (a2v - a1v) + (a2r - a1r);
            float e2 = expf(dd);
            float g0 = 1.0f / (1.0f + e2);
            gwout[2 * t] = g0;
            gwout[2 * t + 1] = e2 * g0;
            topi[2 * t] = i1;
            topi[2 * t + 1] = i2;
        }
    }
}

// ---------------- dispatch: parallel two-level counting scatter ----------------
__global__ __launch_bounds__(1024) void k_disp(const int* __restrict__ topi,
                                               int* __restrict__ cnt,
                                               int* __restrict__ plist) {
    __shared__ int lcnt[NE];
    __shared__ int lbase[NE];
    int tid = threadIdx.x;
    if (tid < NE) lcnt[tid] = 0;
    __syncthreads();
    int p = blockIdx.x * 1024 + tid;
    int e = 0, lr = 0;
    bool act = (p < NPAIR);
    if (act) {
        e = topi[p];
        lr = atomicAdd(&lcnt[e], 1);
    }
    __syncthreads();
    if (tid < NE) {
        int n = lcnt[tid];
        lbase[tid] = n ? atomicAdd(&cnt[tid], n) : 0;
    }
    __syncthreads();
    if (act) {
        int slot = lbase[e] + lr;
        if (slot < CAP) plist[e * CAP + slot] = p;
    }
}

// ---------------- weight convert: f32 -> bf16 fragments, LINEAR layout -------------
__global__ __launch_bounds__(256) void k_wconv(const float* __restrict__ W1,
                                               const float* __restrict__ W2,
                                               unsigned short* __restrict__ w1c,
                                               unsigned short* __restrict__ w2c) {
    int gid = blockIdx.x * 256 + threadIdx.x;
    const int NW1 = NE * 4 * 256 * 4;            // 262144
    if (gid < NW1) {
        int lhi = gid & 3, h = (gid >> 2) & 255, ks = (gid >> 10) & 3, e = gid >> 12;
        int d0 = ks * 32 + lhi * 8;
        unsigned short v[8] __attribute__((aligned(16)));
#pragma unroll
        for (int j = 0; j < 8; j++)
            v[j] = f2bf(W1[((size_t)e * D + d0 + j) * H + h]);
        *(int4*)(w1c + (size_t)gid * 8) = *(int4*)v;
    } else {
        int g = gid - NW1;
        int lhi = g & 3, d = (g >> 2) & 127, ks = (g >> 9) & 7, e = g >> 12;
        int h0 = ks * 32 + lhi * 8;
        unsigned short v[8] __attribute__((aligned(16)));
#pragma unroll
        for (int j = 0; j < 8; j++)
            v[j] = f2bf(W2[((size_t)e * H + h0 + j) * D + d]);
        *(int4*)(w2c + (size_t)g * 8) = *(int4*)v;
    }
}

// ---------------- MoE FFN v8: reg-W + YB bounce + fast gelu + 3 barriers/tile ------
// (reverted from v10: 2-barrier depth-2 prefetch cost +27MB HBM fetch via L2 thrash)
__global__ __launch_bounds__(512, 4) void k_moe(const float* __restrict__ nf,
                                                const int* __restrict__ cnt,
                                                const int* __restrict__ plist,
                                                const unsigned short* __restrict__ w1c,
                                                const float* __restrict__ b1,
                                                const unsigned short* __restrict__ w2c,
                                                const float* __restrict__ b2,
                                                const float* __restrict__ gwbuf,
                                                unsigned short* __restrict__ ybuf) {
    __shared__ __align__(16) char smem[32768];
    const int XA = 0, HL = 8192, YB = 24576;
    int e = blockIdx.x & 63;         // same-expert blocks on same XCD (L2 W reuse)
    int q = blockIdx.x >> 6;
    int n = min(cnt[e], CAP);
    int ntile = (n + TILE_R - 1) / TILE_R;
    if (q >= ntile) return;
    int tid = threadIdx.x;

    int wv = tid >> 6, lane = tid & 63;
    int lhi = lane >> 4, llo = lane & 15;
    int sr = tid >> 4, ss = tid & 15;   // staging role: row, 16B-chunk
    f32x4 zero = {0.f, 0.f, 0.f, 0.f};

    // ---- load W fragments into registers (once per block; coalesced 1KB/wave) ----
    s16x8 w1f[4][2];
#pragma unroll
    for (int ks = 0; ks < 4; ks++)
#pragma unroll
        for (int nt = 0; nt < 2; nt++) {
            int h = wv * 32 + nt * 16 + llo;
            w1f[ks][nt] = *(const s16x8*)(w1c +
                ((size_t)e * 4096 + (ks * 256 + h) * 4 + lhi) * 8);
        }
    s16x8 w2f[8];
    {
        int d = wv * 16 + llo;
#pragma unroll
        for (int ks = 0; ks < 8; ks++)
            w2f[ks] = *(const s16x8*)(w2c +
                ((size_t)e * 4096 + (ks * 128 + d) * 4 + lhi) * 8);
    }

    float vals[8];
    auto loadt = [&](int rt2, float* v) {
        bool ok = false;
        if (rt2 < ntile) {
            int rows2 = min(TILE_R, n - rt2 * TILE_R);
            if (sr < rows2) {
                int p = plist[e * CAP + rt2 * TILE_R + sr];
                const float4* xr = (const float4*)(nf + (size_t)(p >> 1) * D + ss * 8);
                *(float4*)(v + 0) = xr[0];
                *(float4*)(v + 4) = xr[1];
                ok = true;
            }
        }
        if (!ok) {
#pragma unroll
            for (int k = 0; k < 8; k++) v[k] = 0.f;
        }
    };
    loadt(q, vals);   // prefetch first tile (overlaps W-frag loads)

    for (int rt = q; rt < ntile; rt += BQ) {
        int r0 = rt * TILE_R;
        int rows = min(TILE_R, n - r0);

        // ---- write XA from prefetched regs (bf16, swizzled) ----
        {
            unsigned short hb[8] __attribute__((aligned(16)));
#pragma unroll
            for (int k = 0; k < 8; k++) hb[k] = f2bf(vals[k]);
            *(int4*)(smem + XA + sr * 256 + ((ss * 16) ^ ((sr & 7) << 4))) = *(int4*)hb;
        }
        __syncthreads();   // XA ready

        loadt(rt + BQ, vals);   // issue next tile's loads; latency hidden under compute

        // ---- GEMM1: H[32x256] = X @ W1; wave wv owns h-cols [wv*32, +32) ----
        f32x4 acc1[2][2];
#pragma unroll
        for (int mt = 0; mt < 2; mt++)
#pragma unroll
            for (int nt = 0; nt < 2; nt++) acc1[mt][nt] = zero;
#pragma unroll
        for (int ks = 0; ks < 4; ks++) {
            int kb = ks * 64 + lhi * 16;
            s16x8 a0 = *(const s16x8*)(smem + XA + llo * 256        + (kb ^ ((llo & 7) << 4)));
            s16x8 a1 = *(const s16x8*)(smem + XA + (llo + 16) * 256 + (kb ^ ((llo & 7) << 4)));
#pragma unroll
            for (int nt = 0; nt < 2; nt++) {
                acc1[0][nt] = __builtin_amdgcn_mfma_f32_16x16x32_bf16(a0, w1f[ks][nt], acc1[0][nt], 0, 0, 0);
                acc1[1][nt] = __builtin_amdgcn_mfma_f32_16x16x32_bf16(a1, w1f[ks][nt], acc1[1][nt], 0, 0, 0);
            }
        }

        // ---- fast gelu -> HL (bf16, swizzled) ----
#pragma unroll
        for (int mt = 0; mt < 2; mt++)
#pragma unroll
            for (int nt = 0; nt < 2; nt++)
#pragma unroll
                for (int r = 0; r < 4; r++) {
                    int m = mt * 16 + lhi * 4 + r;
                    int hc = wv * 32 + nt * 16 + llo;
                    float hv = acc1[mt][nt][r] + b1[e * H + hc];
                    *(unsigned short*)(smem + HL + m * 512 + ((hc * 2) ^ ((m & 7) << 4))) =
                        f2bf(gelu_f(hv));
                }
        __syncthreads();   // HL ready

        // ---- GEMM2: Y[32x128] = H @ W2; wave wv owns d-cols [wv*16, +16) ----
        f32x4 acc2[2];
        acc2[0] = zero; acc2[1] = zero;
#pragma unroll
        for (int ks = 0; ks < 8; ks++) {
            int kb = ks * 64 + lhi * 16;
            s16x8 a0 = *(const s16x8*)(smem + HL + llo * 512        + (kb ^ ((llo & 7) << 4)));
            s16x8 a1 = *(const s16x8*)(smem + HL + (llo + 16) * 512 + (kb ^ ((llo & 7) << 4)));
            acc2[0] = __builtin_amdgcn_mfma_f32_16x16x32_bf16(a0, w2f[ks], acc2[0], 0, 0, 0);
            acc2[1] = __builtin_amdgcn_mfma_f32_16x16x32_bf16(a1, w2f[ks], acc2[1], 0, 0, 0);
        }

        // ---- stage y (acc2 + b2) into YB (bf16, swizzled) ----
        {
            int d = wv * 16 + llo;
            float bb = b2[e * D + d];
#pragma unroll
            for (int mt = 0; mt < 2; mt++)
#pragma unroll
                for (int r = 0; r < 4; r++) {
                    int m = mt * 16 + lhi * 4 + r;
                    *(unsigned short*)(smem + YB + m * 256 + ((d * 2) ^ ((m & 7) << 4))) =
                        f2bf(acc2[mt][r] + bb);
                }
        }
        __syncthreads();   // YB ready (also fences XA/HL reads for next iter)

        // ---- coalesced ybuf write: thread owns (row sr, 16B chunk ss) ----
        if (sr < rows) {
            int p = plist[e * CAP + r0 + sr];
            float gw = gwbuf[p];
            unsigned short yv[8] __attribute__((aligned(16)));
            *(int4*)yv = *(const int4*)(smem + YB + sr * 256 + ((ss * 16) ^ ((sr & 7) << 4)));
#pragma unroll
            for (int k = 0; k < 8; k++) yv[k] = f2bf(gw * bf2f(yv[k]));
            *(int4*)(ybuf + (size_t)p * D + ss * 8) = *(int4*)yv;
        }
    }
}

// ---------------- BatchNorm: bnpart also writes z = nf + y0 + y1 into nf (in place) --
__global__ __launch_bounds__(256) void k_bnpart(float* __restrict__ nf,
                                                const unsigned short* __restrict__ ybuf,
                                                double* __restrict__ part) {
    int blk = blockIdx.x;
    int col = threadIdx.x & 127;
    int half = threadIdx.x >> 7;
    int r0 = blk * BN_ROWS;
    int r1 = min(r0 + BN_ROWS, N_NODES);
    double s = 0.0, ss = 0.0;
    for (int r = r0 + half; r < r1; r += 2) {
        float v32 = nf[(size_t)r * D + col]
                  + bf2f(ybuf[(size_t)(2 * r) * D + col])
                  + bf2f(ybuf[(size_t)(2 * r + 1) * D + col]);
        nf[(size_t)r * D + col] = v32;        // z for bnapply (nf dead after this)
        double v = (double)v32;
        s += v; ss += v * v;
    }
    __shared__ double sh[2][256];
    sh[0][threadIdx.x] = s; sh[1][threadIdx.x] = ss;
    __syncthreads();
    if (threadIdx.x < 128) {
        part[(size_t)blk * 256 + col]       = sh[0][col] + sh[0][col + 128];
        part[(size_t)blk * 256 + 128 + col] = sh[1][col] + sh[1][col + 128];
    }
}

__global__ void k_bnstats(const double* __restrict__ part,
                          const float* __restrict__ gamma,
                          float* __restrict__ stats) {
    int col = threadIdx.x;   // 128 threads
    double s = 0.0, ss = 0.0;
    for (int b = 0; b < BN_NBLK; b++) {
        s  += part[(size_t)b * 256 + col];
        ss += part[(size_t)b * 256 + 128 + col];
    }
    double mean = s / (double)N_NODES;
    double var = ss / (double)N_NODES - mean * mean;
    stats[col] = (float)mean;
    stats[128 + col] = gamma[col] * (float)(1.0 / sqrt(var + 1e-5));
}

// ---------------- bnapply v2: in-place on z (out), float4 ----------------
__global__ __launch_bounds__(256) void k_bnapply(const float* __restrict__ stats,
                                                 const float* __restrict__ beta,
                                                 float* __restrict__ out) {
    int i = blockIdx.x * blockDim.x + threadIdx.x;   // float4 index
    if (i >= N_NODES * (D / 4)) return;
    int q = i & 31;
    int c0 = q * 4;
    float4 z = ((const float4*)out)[i];
    float4 r;
    r.x = (z.x - stats[c0 + 0]) * stats[128 + c0 + 0] + beta[c0 + 0];
    r.y = (z.y - stats[c0 + 1]) * stats[128 + c0 + 1] + beta[c0 + 1];
    r.z = (z.z - stats[c0 + 2]) * stats[128 + c0 + 2] + beta[c0 + 2];
    r.w = (z.w - stats[c0 + 3]) * stats[128 + c0 + 3] + beta[c0 + 3];
    ((float4*)out)[i] = r;
}

// ---------------- launch ----------------
extern "C" void kernel_launch(void* const* d_in, const int* in_sizes, int n_in,
                              void* d_out, int out_size, void* d_ws, size_t ws_size,
                              hipStream_t stream) {
    const float* feats   = (const float*)d_in[0];
    const int*   esrc    = (const int*)d_in[1];
    const int*   edst    = (const int*)d_in[2];
    const float* W_conv  = (const float*)d_in[3];
    const float* b_conv  = (const float*)d_in[4];
    const float* gate_W  = (const float*)d_in[5];
    const float* gate_b  = (const float*)d_in[6];
    const float* W1      = (const float*)d_in[7];
    const float* b1      = (const float*)d_in[8];
    const float* W2      = (const float*)d_in[9];
    const float* b2      = (const float*)d_in[10];
    const float* bn_g    = (const float*)d_in[11];
    const float* bn_b    = (const float*)d_in[12];
    float* out = (float*)d_out;   // doubles as new_feats / z storage

    char* ws = (char*)d_ws;
    size_t off = 0;
    auto rup = [](size_t x) { return (x + 255) & ~(size_t)255; };
    int*    deg    = (int*)   (ws + off); off += rup((size_t)N_NODES * 4);
    int*    cursor = (int*)   (ws + off); off += rup((size_t)N_NODES * 4);
    int*    cnt    = (int*)   (ws + off); off += 256;
    int*    rcnt   = (int*)   (ws + off); off += 256;
    size_t zero_bytes = off;                 // deg + cursor + cnt + rcnt (~400 KB)
    float*  invs   = (float*) (ws + off); off += rup((size_t)N_NODES * 4);
    int*    rowptr = (int*)   (ws + off); off += rup((size_t)(N_NODES + 1) * 4);
    int*    csr    = (int*)   (ws + off); off += rup((size_t)N_EDGES * 4);
    float*  gwbuf  = (float*) (ws + off); off += rup((size_t)NPAIR * 4);
    int*    topi   = (int*)   (ws + off); off += rup((size_t)NPAIR * 4);
    int*    redo   = (int*)   (ws + off); off += rup((size_t)N_NODES * 4);
    int*    plist  = (int*)   (ws + off); off += rup((size_t)NE * CAP * 4);
    double* part   = (double*)(ws + off); off += rup((size_t)BN_NBLK * 256 * 8);
    float*  stats  = (float*) (ws + off); off += 1024;
    unsigned short* w1c  = (unsigned short*)(ws + off); off += rup((size_t)NE * D * H * 2); // 4 MB
    unsigned short* w2c  = (unsigned short*)(ws + off); off += rup((size_t)NE * D * H * 2); // 4 MB
    unsigned short* wchi = (unsigned short*)(ws + off); off += rup((size_t)D * D * 2);      // 32 KB
    unsigned short* wclo = (unsigned short*)(ws + off); off += rup((size_t)D * D * 2);      // 32 KB
    unsigned short* wghi = (unsigned short*)(ws + off); off += rup((size_t)D * NE * 2);     // 16 KB
    unsigned short* wglo = (unsigned short*)(ws + off); off += rup((size_t)D * NE * 2);     // 16 KB
    unsigned short* ybuf = (unsigned short*)(ws + off); off += rup((size_t)NPAIR * D * 2);  // 25.6 MB
    float*  agg    = (float*)ybuf;   // lifetime-disjoint alias (agg dead before k_moe writes ybuf)
    (void)ws_size; (void)in_sizes; (void)n_in; (void)out_size;

    hipMemsetAsync(d_ws, 0, zero_bytes, stream);

    k_wconv<<<2 * NE * 4 * 256 * 4 / 256, 256, 0, stream>>>(W1, W2, w1c, w2c);
    k_wcsplit<<<8, 256, 0, stream>>>(W_conv, wchi, wclo);
    k_wgsplit<<<4, 256, 0, stream>>>(gate_W, wghi, wglo);
    k_deg<<<(N_EDGES + 255) / 256, 256, 0, stream>>>(edst, deg);
    k_invsqrt<<<(N_NODES + 255) / 256, 256, 0, stream>>>(deg, invs);
    k_scan<<<1, 1024, 0, stream>>>(deg, rowptr);
    k_scatter<<<(N_EDGES + 255) / 256, 256, 0, stream>>>(esrc, edst, rowptr, cursor, csr);
    k_gather<<<(N_NODES + 3) / 4, 256, 0, stream>>>(feats, rowptr, csr, invs, agg);
    k_convgate<<<(N_NODES + TILE_R - 1) / TILE_R, 512, 0, stream>>>(
        agg, wchi, wclo, b_conv, wghi, wglo, gate_b, out, gwbuf, topi, rcnt, redo);
    k_gfix<<<128, 256, 0, stream>>>(out, gate_W, gate_b, rcnt, redo, gwbuf, topi);
    k_disp<<<(NPAIR + 1023) / 1024, 1024, 0, stream>>>(topi, cnt, plist);
    k_moe<<<NE * BQ, 512, 0, stream>>>(out, cnt, plist, w1c, b1, w2c, b2, gwbuf, ybuf);
    k_bnpart<<<BN_NBLK, 256, 0, stream>>>(out, ybuf, part);
    k_bnstats<<<1, 128, 0, stream>>>(part, bn_g, stats);
    k_bnapply<<<(N_NODES * (D / 4) + 255) / 256, 256, 0, stream>>>(stats, bn_b, out);
}